// Round 1
// baseline (1232.684 us; speedup 1.0000x reference)
//
#include <hip/hip_runtime.h>

namespace {
constexpr int kB = 256;
constexpr int kS = 2048;
constexpr int kV = 10;
constexpr int kE = 32;
constexpr int kH = 64;
constexpr int kO = 10;
constexpr int kT = 16;      // recurrence steps per tile (logits batched per tile)
constexpr int kPad = 68;    // padded LDS row stride in floats: 16B-aligned rows + bank spread

__device__ __forceinline__ float rlane(float v, int lane) {
    return __int_as_float(__builtin_amdgcn_readlane(__float_as_int(v), lane));
}

__device__ __forceinline__ float fast_tanh(float x) {
    // tanh(x) = (e^{2x}-1)/(e^{2x}+1); clamp so exp never overflows (tanh(9) == 1 in f32)
    float xc = fminf(fmaxf(x, -9.0f), 9.0f);
    float e  = __expf(2.0f * xc);
    return (e - 1.0f) * __builtin_amdgcn_rcpf(e + 1.0f);
}

__global__ __launch_bounds__(64, 1)
void rnn_fused(const int* __restrict__ num1, const int* __restrict__ num2,
               const float* __restrict__ embed, const float* __restrict__ Wx,
               const float* __restrict__ Wh, const float* __restrict__ bias,
               const float* __restrict__ Wd, const float* __restrict__ bd,
               float* __restrict__ out)
{
    const int row = blockIdx.x;   // one sequence per block (single wave)
    const int j   = threadIdx.x;  // lane j owns hidden unit j

    // xw table: only 100 distinct (num1,num2) pairs -> whole input projection precomputed
    __shared__ __align__(16) float TT[kV * kV][kH];   // 25.6 KB
    __shared__ __align__(16) float hbuf[kT][kPad];    // h history ring for batched logits
    __shared__ __align__(16) float WdT[kO][kPad];     // Wd transposed for float4 dot reads
    __shared__ float bdL[kO];

    // ---- one-time per-block setup ----
    {
        float wxc[2 * kE];
        #pragma unroll
        for (int k = 0; k < 2 * kE; ++k) wxc[k] = Wx[k * kH + j];  // Wx column j
        float bj = bias[j];
        float t1[kV], t2[kV];
        #pragma unroll
        for (int v = 0; v < kV; ++v) {
            float a0 = 0.f, a1 = 0.f;
            #pragma unroll
            for (int k = 0; k < kE; ++k) {
                float e = embed[v * kE + k];   // lane-uniform -> s_load
                a0 = fmaf(e, wxc[k], a0);
                a1 = fmaf(e, wxc[kE + k], a1);
            }
            t1[v] = a0; t2[v] = a1;
        }
        #pragma unroll
        for (int v1 = 0; v1 < kV; ++v1)
            #pragma unroll
            for (int v2 = 0; v2 < kV; ++v2)
                TT[v1 * kV + v2][j] = t1[v1] + t2[v2] + bj;
        #pragma unroll
        for (int o = 0; o < kO; ++o) WdT[o][j] = Wd[j * kO + o];
        if (j < kO) bdL[j] = bd[j];
    }

    float whc[kH];                 // Wh column j in registers
    #pragma unroll
    for (int i = 0; i < kH; ++i) whc[i] = Wh[i * kH + j];

    __syncthreads();

    const int lane16 = j & 15;
    const int nb = row * kS;
    // lane L holds the xw-table index for local step (L & 15) of the current tile
    int idxv = num1[nb + lane16] * kV + num2[nb + lane16];

    float hv = 0.0f;               // h_j, lives in a register for the whole scan

    for (int t0 = 0; t0 < kS; t0 += kT) {
        // prefetch next tile's indices (hides HBM latency under this tile's compute)
        int idx_next = 0;
        if (t0 + kT < kS) {
            int tt = nb + t0 + kT + lane16;
            idx_next = num1[tt] * kV + num2[tt];
        }

        // prefetch all 16 xw rows for this tile from LDS table
        float xw[kT];
        #pragma unroll
        for (int tl = 0; tl < kT; ++tl) {
            int sidx = __builtin_amdgcn_readlane(idxv, tl);   // uniform
            xw[tl] = TT[sidx][j];
        }

        // ---- 16 sequential recurrence steps ----
        #pragma unroll
        for (int tl = 0; tl < kT; ++tl) {
            float a0 = xw[tl], a1 = 0.f, a2 = 0.f, a3 = 0.f;
            #pragma unroll
            for (int i = 0; i < kH; i += 4) {
                a0 = fmaf(rlane(hv, i + 0), whc[i + 0], a0);
                a1 = fmaf(rlane(hv, i + 1), whc[i + 1], a1);
                a2 = fmaf(rlane(hv, i + 2), whc[i + 2], a2);
                a3 = fmaf(rlane(hv, i + 3), whc[i + 3], a3);
            }
            hv = fast_tanh((a0 + a1) + (a2 + a3));
            hbuf[tl][j] = hv;
        }
        __syncthreads();   // single wave: cheap; forces LDS visibility for logits pass

        // ---- batched logits for the tile: 160 outputs over 64 lanes ----
        const int obase = row * (kS * kO) + t0 * kO;
        #pragma unroll
        for (int r = 0; r < 3; ++r) {
            int f = r * 64 + j;                  // flat (t_local, o) index
            if (f < kT * kO) {
                int tl = f / kO;
                int o  = f - tl * kO;
                const float4* hb4 = reinterpret_cast<const float4*>(&hbuf[tl][0]);
                const float4* wd4 = reinterpret_cast<const float4*>(&WdT[o][0]);
                float a0 = bdL[o], a1 = 0.f, a2 = 0.f, a3 = 0.f;
                #pragma unroll
                for (int c = 0; c < kH / 4; ++c) {
                    float4 h4 = hb4[c];
                    float4 w4 = wd4[c];
                    a0 = fmaf(h4.x, w4.x, a0);
                    a1 = fmaf(h4.y, w4.y, a1);
                    a2 = fmaf(h4.z, w4.z, a2);
                    a3 = fmaf(h4.w, w4.w, a3);
                }
                out[obase + f] = (a0 + a1) + (a2 + a3);   // coalesced
            }
        }
        __syncthreads();   // protect hbuf before next tile overwrites it
        idxv = idx_next;
    }
}
} // namespace

extern "C" void kernel_launch(void* const* d_in, const int* in_sizes, int n_in,
                              void* d_out, int out_size, void* d_ws, size_t ws_size,
                              hipStream_t stream) {
    (void)in_sizes; (void)n_in; (void)d_ws; (void)ws_size; (void)out_size;
    rnn_fused<<<dim3(kB), dim3(64), 0, stream>>>(
        (const int*)d_in[0], (const int*)d_in[1],
        (const float*)d_in[2], (const float*)d_in[3],
        (const float*)d_in[4], (const float*)d_in[5],
        (const float*)d_in[6], (const float*)d_in[7],
        (float*)d_out);
}

// Round 2
// 831.988 us; speedup vs baseline: 1.4816x; 1.4816x over previous
//
#include <hip/hip_runtime.h>

namespace {
constexpr int kB = 256;
constexpr int kS = 2048;
constexpr int kV = 10;
constexpr int kE = 32;
constexpr int kH = 64;
constexpr int kO = 10;
constexpr int kT = 16;      // recurrence steps per tile (logits batched per tile)
constexpr int kPad = 68;    // padded LDS row stride in floats

__device__ __forceinline__ float rlane(float v, int lane) {
    return __int_as_float(__builtin_amdgcn_readlane(__float_as_int(v), lane));
}

__device__ __forceinline__ float fast_tanh(float x) {
    // clamp via single v_med3_f32 (tanh(9)==1 in fp32; also guards inf/nan path)
    float xc = __builtin_amdgcn_fmed3f(x, -9.0f, 9.0f);
    float e  = __expf(2.0f * xc);
    return (e - 1.0f) * __builtin_amdgcn_rcpf(e + 1.0f);
}

__global__ __launch_bounds__(64, 1)
void rnn_fused(const int* __restrict__ num1, const int* __restrict__ num2,
               const float* __restrict__ embed, const float* __restrict__ Wx,
               const float* __restrict__ Wh, const float* __restrict__ bias,
               const float* __restrict__ Wd, const float* __restrict__ bd,
               float* __restrict__ out)
{
    const int row = blockIdx.x;   // one sequence per block (single wave)
    const int j   = threadIdx.x;  // lane j owns hidden unit j

    __shared__ __align__(16) float TT[kV * kV][kH];   // 100 possible xw rows
    __shared__ __align__(16) float hbuf[kT][kPad];    // h history for batched logits
    __shared__ __align__(16) float WdT[kO][kPad];
    __shared__ float bdL[kO];

    // ---- one-time per-block setup ----
    {
        float wxc[2 * kE];
        #pragma unroll
        for (int k = 0; k < 2 * kE; ++k) wxc[k] = Wx[k * kH + j];  // Wx column j
        float bj = bias[j];
        float t1[kV], t2[kV];
        #pragma unroll
        for (int v = 0; v < kV; ++v) {
            float a0 = 0.f, a1 = 0.f;
            #pragma unroll
            for (int k = 0; k < kE; ++k) {
                float e = embed[v * kE + k];   // lane-uniform -> s_load
                a0 = fmaf(e, wxc[k], a0);
                a1 = fmaf(e, wxc[kE + k], a1);
            }
            t1[v] = a0; t2[v] = a1;
        }
        #pragma unroll
        for (int v1 = 0; v1 < kV; ++v1)
            #pragma unroll
            for (int v2 = 0; v2 < kV; ++v2)
                TT[v1 * kV + v2][j] = t1[v1] + t2[v2] + bj;
        #pragma unroll
        for (int o = 0; o < kO; ++o) WdT[o][j] = Wd[j * kO + o];
        if (j < kO) bdL[j] = bd[j];
    }

    float whc[kH];                 // Wh column j in registers
    #pragma unroll
    for (int i = 0; i < kH; ++i) whc[i] = Wh[i * kH + j];

    __syncthreads();

    const int lane16 = j & 15;
    const int nb = row * kS;
    int idxv = num1[nb + lane16] * kV + num2[nb + lane16];

    float hv = 0.0f;               // h_j, register-resident for the whole scan

    for (int t0 = 0; t0 < kS; t0 += kT) {
        // prefetch next tile's indices
        int idx_next = 0;
        if (t0 + kT < kS) {
            int tt = nb + t0 + kT + lane16;
            idx_next = num1[tt] * kV + num2[tt];
        }

        // prefetch all 16 xw rows for this tile from the LDS table
        float xw[kT];
        #pragma unroll
        for (int tl = 0; tl < kT; ++tl) {
            int sidx = __builtin_amdgcn_readlane(idxv, tl);   // uniform
            xw[tl] = TT[sidx][j];
        }

        // ---- 16 sequential recurrence steps ----
        #pragma unroll
        for (int tl = 0; tl < kT; ++tl) {
            // Phase 1: batch ALL readlanes back-to-back. Independent of each
            // other -> issue-limited. Keeping them apart from their consumers
            // kills the VALU-writes-SGPR -> VALU-reads-SGPR wait states that
            // dominated the previous version (~1390 cy/step measured).
            float sc[kH];
            #pragma unroll
            for (int i = 0; i < kH; ++i) sc[i] = rlane(hv, i);
            __builtin_amdgcn_sched_barrier(0);   // do NOT re-interleave
            // Phase 2: 64 FMAs, 4 independent accumulator chains
            float a0 = xw[tl], a1 = 0.f, a2 = 0.f, a3 = 0.f;
            #pragma unroll
            for (int i = 0; i < kH; i += 4) {
                a0 = fmaf(sc[i + 0], whc[i + 0], a0);
                a1 = fmaf(sc[i + 1], whc[i + 1], a1);
                a2 = fmaf(sc[i + 2], whc[i + 2], a2);
                a3 = fmaf(sc[i + 3], whc[i + 3], a3);
            }
            hv = fast_tanh((a0 + a1) + (a2 + a3));
            hbuf[tl][j] = hv;
        }
        __syncthreads();

        // ---- batched logits for the tile: 160 outputs over 64 lanes ----
        const int obase = row * (kS * kO) + t0 * kO;
        #pragma unroll
        for (int r = 0; r < 3; ++r) {
            int f = r * 64 + j;                  // flat (t_local, o) index
            if (f < kT * kO) {
                int tl = f / kO;
                int o  = f - tl * kO;
                const float4* hb4 = reinterpret_cast<const float4*>(&hbuf[tl][0]);
                const float4* wd4 = reinterpret_cast<const float4*>(&WdT[o][0]);
                float a0 = bdL[o], a1 = 0.f, a2 = 0.f, a3 = 0.f;
                #pragma unroll
                for (int c = 0; c < kH / 4; ++c) {
                    float4 h4 = hb4[c];
                    float4 w4 = wd4[c];
                    a0 = fmaf(h4.x, w4.x, a0);
                    a1 = fmaf(h4.y, w4.y, a1);
                    a2 = fmaf(h4.z, w4.z, a2);
                    a3 = fmaf(h4.w, w4.w, a3);
                }
                out[obase + f] = (a0 + a1) + (a2 + a3);   // coalesced
            }
        }
        __syncthreads();
        idxv = idx_next;
    }
}
} // namespace

extern "C" void kernel_launch(void* const* d_in, const int* in_sizes, int n_in,
                              void* d_out, int out_size, void* d_ws, size_t ws_size,
                              hipStream_t stream) {
    (void)in_sizes; (void)n_in; (void)d_ws; (void)ws_size; (void)out_size;
    rnn_fused<<<dim3(kB), dim3(64), 0, stream>>>(
        (const int*)d_in[0], (const int*)d_in[1],
        (const float*)d_in[2], (const float*)d_in[3],
        (const float*)d_in[4], (const float*)d_in[5],
        (const float*)d_in[6], (const float*)d_in[7],
        (float*)d_out);
}